// Round 5
// baseline (863.437 us; speedup 1.0000x reference)
//
#include <hip/hip_runtime.h>
#include <hip/hip_bf16.h>
#include <hip/hip_cooperative_groups.h>

namespace cg = cooperative_groups;

#define NN 100000
#define NE 1200000
#define SCAN_B 256
#define NBLK ((NN + SCAN_B - 1) / SCAN_B)   // 391
#define NE4 (NE / 4)                         // 300000
#define XCD_N 8
#define NPX (NN / XCD_N)                     // 12500 nodes per XCD
#define BGRID 1024                           // cooperative grid (4 blocks/CU)

// ---------------- fused CSR build: zero + count + scan + fill, one cooperative kernel ----------
// XCD-ownership (proven R4): block b (XCD = b&7) stripes the full edge list with its
// XCD's sibling blocks and touches only dsts in its 12500-node range -> deg/cursor/csr
// lines are written by exactly one XCD (R3 showed 85MB HBM writes for 4.8MB payload
// without this). grid.sync() replaces 6 separate dispatches.
__global__ __launch_bounds__(256) void build_kernel(const int* __restrict__ esrc,
                                                    const int* __restrict__ edst,
                                                    int* __restrict__ deg,
                                                    float* __restrict__ dinv,
                                                    int* __restrict__ rowptr,
                                                    int* __restrict__ rp2,
                                                    int* __restrict__ bsum,
                                                    int* __restrict__ boff,
                                                    int* __restrict__ csr,
                                                    float* __restrict__ gp) {
    cg::grid_group grid = cg::this_grid();
    __shared__ int s[512];
    int tid = threadIdx.x;
    int gidx = blockIdx.x * 256 + tid;
    const int gstride = BGRID * 256;
    int xcd = blockIdx.x & 7;
    int sub = blockIdx.x >> 3;
    const int nsub = BGRID >> 3;
    int lo = xcd * NPX;

    // phase Z: zero deg + pool partials
    for (int i = gidx; i < NN; i += gstride) deg[i] = 0;
    if (gidx < 64 * 64) gp[gidx] = 0.f;
    grid.sync();

    // phase C: count (XCD-owned, non-returning atomics)
    for (int i = sub * 256 + tid; i < NE4; i += nsub * 256) {
        int4 d = ((const int4*)edst)[i];
        if ((unsigned)(d.x - lo) < NPX) atomicAdd(&deg[d.x], 1);
        if ((unsigned)(d.y - lo) < NPX) atomicAdd(&deg[d.y], 1);
        if ((unsigned)(d.z - lo) < NPX) atomicAdd(&deg[d.z], 1);
        if ((unsigned)(d.w - lo) < NPX) atomicAdd(&deg[d.w], 1);
    }
    grid.sync();

    // phase S1: per-256-chunk inclusive scan (+ fused dinv), blocks 0..NBLK-1
    if (blockIdx.x < NBLK) {
        int n = blockIdx.x * 256 + tid;
        int d = (n < NN) ? deg[n] : 0;
        if (n < NN) dinv[n] = rsqrtf((float)(d + 1));   // +1 self loop
        s[tid] = d;
        for (int off = 1; off < 256; off <<= 1) {
            __syncthreads();
            int t = (tid >= off) ? s[tid - off] : 0;
            __syncthreads();
            s[tid] += t;
        }
        if (n <= NN) rowptr[n] = s[tid] - d;            // exclusive, partial
        if (tid == 255) bsum[blockIdx.x] = s[tid];
    }
    grid.sync();

    // phase S2: block 0 scans the NBLK block sums (padded to 512, 2 slots/thread)
    if (blockIdx.x == 0) {
        int v0 = (tid < NBLK) ? bsum[tid] : 0;
        int v1 = (tid + 256 < NBLK) ? bsum[tid + 256] : 0;
        s[tid] = v0; s[tid + 256] = v1;
        __syncthreads();
        for (int off = 1; off < 512; off <<= 1) {
            int a0 = (tid >= off) ? s[tid - off] : 0;
            int a1 = (tid + 256 >= off) ? s[tid + 256 - off] : 0;
            __syncthreads();
            s[tid] += a0; s[tid + 256] += a1;
            __syncthreads();
        }
        if (tid < NBLK) boff[tid] = s[tid] - v0;        // exclusive block offsets
        if (tid + 256 < NBLK) boff[tid + 256] = s[tid + 256] - v1;
    }
    grid.sync();

    // phase S3: finalize rowptr, write fill cursors
    for (int n = gidx; n < NN; n += gstride) {
        int v = rowptr[n] + boff[n >> 8];
        rowptr[n] = v;
        rp2[n] = v;
    }
    if (gidx == 0) rowptr[NN] = NE;
    grid.sync();

    // phase F: fill (XCD-owned cursors and csr lines)
    for (int i = sub * 256 + tid; i < NE4; i += nsub * 256) {
        int4 d  = ((const int4*)edst)[i];
        int4 sr = ((const int4*)esrc)[i];
        if ((unsigned)(d.x - lo) < NPX) { int p = atomicAdd(&rp2[d.x], 1); csr[p] = sr.x; }
        if ((unsigned)(d.y - lo) < NPX) { int p = atomicAdd(&rp2[d.y], 1); csr[p] = sr.y; }
        if ((unsigned)(d.z - lo) < NPX) { int p = atomicAdd(&rp2[d.z], 1); csr[p] = sr.z; }
        if ((unsigned)(d.w - lo) < NPX) { int p = atomicAdd(&rp2[d.w], 1); csr[p] = sr.w; }
    }
}

// ---------------- per-node matmul, fused finalize of previous layer ----------------
// MODE 0: v = x[n][f] (f32 input)
// MODE 1: v = relu(dinv[n]*a[n][f]+bias[f]) with a in bf16 (halved round-trip traffic)
// writes u[n] = bf16( dinv[n] * (v_row @ W) )
template <int MODE>
__global__ __launch_bounds__(256) void mm_kernel(const void* __restrict__ in,
                                                 const float* __restrict__ W,
                                                 const float* __restrict__ bias,
                                                 const float* __restrict__ dinv,
                                                 __hip_bfloat16* __restrict__ u) {
    __shared__ float Ws[64 * 64];
    __shared__ float hrow[4][64];
    int tid = threadIdx.x;
    {   // stage W (16 KB) via float4
        const float4* Wv = (const float4*)W;
        float4* Wsv = (float4*)Ws;
        #pragma unroll
        for (int i = 0; i < 4; ++i) Wsv[tid + 256 * i] = Wv[tid + 256 * i];
    }
    int local = tid >> 6;            // node within block
    int f = tid & 63;                // feature
    int n = blockIdx.x * 4 + local;  // NN divisible by 4
    float din = dinv[n];
    float v;
    if (MODE == 0) {
        v = ((const float*)in)[n * 64 + f];
    } else {
        v = __bfloat162float(((const __hip_bfloat16*)in)[n * 64 + f]);
        v = fmaxf(fmaf(din, v, bias[f]), 0.f);
    }
    hrow[local][f] = v;
    __syncthreads();
    float acc = 0.f;
    #pragma unroll
    for (int k = 0; k < 64; ++k)
        acc = fmaf(hrow[local][k], Ws[k * 64 + f], acc);
    u[n * 64 + f] = __float2bfloat16(din * acc);
}

// ---------------- aggregation core, G=8 (proven ~68us/layer floor) ----------------
__device__ __forceinline__ void acc_bf8(float acc[8], uint4 v) {
    acc[0] += __uint_as_float(v.x << 16);
    acc[1] += __uint_as_float(v.x & 0xffff0000u);
    acc[2] += __uint_as_float(v.y << 16);
    acc[3] += __uint_as_float(v.y & 0xffff0000u);
    acc[4] += __uint_as_float(v.z << 16);
    acc[5] += __uint_as_float(v.z & 0xffff0000u);
    acc[6] += __uint_as_float(v.w << 16);
    acc[7] += __uint_as_float(v.w & 0xffff0000u);
}

__device__ __forceinline__ unsigned packbf2(float lof, float hif) {
    __hip_bfloat16 l = __float2bfloat16(lof), h = __float2bfloat16(hif);
    unsigned short ul, uh;
    __builtin_memcpy(&ul, &l, 2);
    __builtin_memcpy(&uh, &h, 2);
    return ((unsigned)uh << 16) | ul;
}

// On exit: acc[0..8) = aggregated row (self + neighbors) for features
// [fo*8, fo*8+8), replicated across the 8 groups.
__device__ __forceinline__ void agg_row(const int* __restrict__ rowptr,
                                        const int* __restrict__ csr,
                                        const uint4* __restrict__ u4,
                                        int n, int lane, int grp, int fo,
                                        float acc[8]) {
    float acc2[8];
    #pragma unroll
    for (int i = 0; i < 8; ++i) { acc[i] = 0.f; acc2[i] = 0.f; }
    int start = rowptr[n], end = rowptr[n + 1];
    int deg = end - start;
    int cidx = -1;
    if (lane < deg) cidx = csr[start + lane];        // one coalesced row load
    if (grp == 0) acc_bf8(acc, u4[n * 8 + fo]);      // self loop
    int s0 = __shfl(cidx, grp);                      // sweep 0: edges 0..7
    int s1 = __shfl(cidx, grp + 8);                  // sweep 1: edges 8..15
    if (grp < deg) acc_bf8(acc, u4[s0 * 8 + fo]);
    if (grp + 8 < deg) acc_bf8(acc2, u4[s1 * 8 + fo]);
    int dcap = deg < 64 ? deg : 64;
    for (int j = grp + 16; j < dcap; j += 8) {       // deg in (16,64]
        int s = __shfl(cidx, j);
        acc_bf8(acc, u4[s * 8 + fo]);
    }
    for (int base = start + 64; base < end; base += 64) {  // deg > 64: ~never
        int bcnt = end - base; if (bcnt > 64) bcnt = 64;
        int c2 = (lane < bcnt) ? csr[base + lane] : -1;
        for (int j = grp; j < bcnt; j += 8) {
            int s = __shfl(c2, j);
            acc_bf8(acc2, u4[s * 8 + fo]);
        }
    }
    #pragma unroll
    for (int i = 0; i < 8; ++i) {                    // merge sweeps + 8 groups
        float v = acc[i] + acc2[i];
        v += __shfl_xor(v, 8);
        v += __shfl_xor(v, 16);
        v += __shfl_xor(v, 32);
        acc[i] = v;
    }
}

// ---------------- aggregate (POOL=0: a[n][:]=agg in bf16; POOL=1: fused global pool) ------------
// one wave per node, 100000 waves: max TLP, no serial nodes (R1/R2 lesson).
template <int POOL>
__global__ __launch_bounds__(256, 8) void agg_kernel(const int* __restrict__ rowptr,
                                                     const int* __restrict__ csr,
                                                     const uint4* __restrict__ uin,
                                                     const float* __restrict__ dinv,
                                                     __hip_bfloat16* __restrict__ a,
                                                     float* __restrict__ gp) {
    __shared__ float gpart[64];
    int tid = threadIdx.x;
    if (POOL) {
        if (tid < 64) gpart[tid] = 0.f;
        __syncthreads();
    }
    int lane = tid & 63;
    int grp = lane >> 3;
    int fo = lane & 7;
    int n = blockIdx.x * 4 + (tid >> 6);              // NN divisible by 4
    float acc[8];
    agg_row(rowptr, csr, uin, n, lane, grp, fo, acc);
    if (POOL) {
        if (grp == 0) {                               // lanes 0..7 hold the full row
            float din = dinv[n];
            #pragma unroll
            for (int i = 0; i < 8; ++i) atomicAdd(&gpart[fo * 8 + i], din * acc[i]);
        }
        __syncthreads();
        if (tid < 64) atomicAdd(&gp[(blockIdx.x & 63) * 64 + tid], gpart[tid]);
    } else {
        if (grp == 0) {                               // 8 lanes x 16B bf16 = the 128B row
            uint4 pv;
            pv.x = packbf2(acc[0], acc[1]);
            pv.y = packbf2(acc[2], acc[3]);
            pv.z = packbf2(acc[4], acc[5]);
            pv.w = packbf2(acc[6], acc[7]);
            ((uint4*)a)[n * 8 + fo] = pv;
        }
    }
}

// ---------------- head: g = colsum(gp) + N*b2;  out = g @ Wl + bl ----------------
__global__ __launch_bounds__(64) void head_kernel(const float* __restrict__ gp,
                                                  const float* __restrict__ b2,
                                                  const float* __restrict__ Wl,
                                                  const float* __restrict__ bl,
                                                  float* __restrict__ out) {
    int t = threadIdx.x;  // one wave
    float s = 0.f;
    #pragma unroll 8
    for (int r = 0; r < 64; ++r) s += gp[r * 64 + t];
    float gf = s + (float)NN * b2[t];
    #pragma unroll
    for (int c = 0; c < 10; ++c) {
        float p = gf * Wl[t * 10 + c];
        #pragma unroll
        for (int off = 32; off > 0; off >>= 1) p += __shfl_down(p, off);
        if (t == 0) out[c] = p + bl[c];
    }
}

extern "C" void kernel_launch(void* const* d_in, const int* in_sizes, int n_in,
                              void* d_out, int out_size, void* d_ws, size_t ws_size,
                              hipStream_t stream) {
    const float* x  = (const float*)d_in[0];
    const int* eidx = (const int*)d_in[1];
    const int* esrc = (const int*)eidx;   // edge_idx[0]
    const int* edst = (const int*)eidx + NE;   // edge_idx[1]
    const float* W0 = (const float*)d_in[2];
    const float* b0 = (const float*)d_in[3];
    const float* W1 = (const float*)d_in[4];
    const float* b1 = (const float*)d_in[5];
    const float* W2 = (const float*)d_in[6];
    const float* b2 = (const float*)d_in[7];
    const float* Wl = (const float*)d_in[8];
    const float* bl = (const float*)d_in[9];
    float* out = (float*)d_out;

    // workspace layout (4-byte units); u and a are 16B-aligned
    float* ws = (float*)d_ws;
    size_t off = 0;
    int*   deg    = (int*)(ws + off); off += NN;
    float* dinv   =        ws + off;  off += NN;
    __hip_bfloat16* u = (__hip_bfloat16*)(ws + off); off += (size_t)NN * 32;  // bf16 N*64
    __hip_bfloat16* a = (__hip_bfloat16*)(ws + off); off += (size_t)NN * 32;  // bf16 N*64
    float* gp     =        ws + off;  off += 64 * 64;   // pool partials
    int*   rowptr = (int*)(ws + off); off += NN + 1;
    int*   rp2    = (int*)(ws + off); off += NN;
    int*   bsum   = (int*)(ws + off); off += 512;
    int*   boff   = (int*)(ws + off); off += 512;
    int*   csr    = (int*)(ws + off); off += NE;

    // one cooperative dispatch builds everything (zero + count + scan + dinv + fill)
    {
        void* args[] = {(void*)&esrc, (void*)&edst, (void*)&deg, (void*)&dinv,
                        (void*)&rowptr, (void*)&rp2, (void*)&bsum, (void*)&boff,
                        (void*)&csr, (void*)&gp};
        hipLaunchCooperativeKernel((void*)build_kernel, dim3(BGRID), dim3(256),
                                   args, 0, stream);
    }

    // layer 0
    mm_kernel<0><<<NN / 4, 256, 0, stream>>>(x, W0, nullptr, dinv, u);
    agg_kernel<0><<<NN / 4, 256, 0, stream>>>(rowptr, csr, (const uint4*)u, dinv, a, gp);
    // layer 1
    mm_kernel<1><<<NN / 4, 256, 0, stream>>>(a, W1, b0, dinv, u);
    agg_kernel<0><<<NN / 4, 256, 0, stream>>>(rowptr, csr, (const uint4*)u, dinv, a, gp);
    // layer 2
    mm_kernel<1><<<NN / 4, 256, 0, stream>>>(a, W2, b1, dinv, u);
    // fused: agg(layer2) + global pool (dinv folded; N*b2 added in head)
    agg_kernel<1><<<NN / 4, 256, 0, stream>>>(rowptr, csr, (const uint4*)u, dinv, a, gp);
    head_kernel<<<1, 64, 0, stream>>>(gp, b2, Wl, bl, out);
}

// Round 6
// 345.564 us; speedup vs baseline: 2.4986x; 2.4986x over previous
//
#include <hip/hip_runtime.h>
#include <hip/hip_bf16.h>

#define NN 100000
#define NE 1200000
#define NE4 (NE / 4)                         // 300000
#define XCD_N 8
#define NPX (NN / XCD_N)                     // 12500 nodes per XCD
#define CAP 64                               // bucket capacity (P(deg>64) ~ 15 sigma)
#define SPILL_MAX 4096

// ---------------- single-pass CSR-bucket build, XCD-partitioned ----------------
// block b (XCD = b&7, normal dispatch only -- R5 showed coop launch breaks this
// mapping) stripes the full edge list with its XCD's sibling blocks and handles
// only dsts in its 12500-node range: deg lines and bucket lines are written by
// exactly one XCD -> L2-local atomics, dirty lines evict once (R3: 85MB HBM
// writes for 4.8MB payload without ownership). Returning atomicAdd gives the
// slot; deg ends as the true degree. Slots >= CAP go to a spill list (never in
// practice; drained inside agg for correctness).
__global__ __launch_bounds__(256) void bucket_fill_kernel(const int* __restrict__ esrc,
                                                          const int* __restrict__ edst,
                                                          int* __restrict__ deg,
                                                          int* __restrict__ bucket,
                                                          int* __restrict__ spill,
                                                          int* __restrict__ spill_cnt) {
    int xcd = blockIdx.x & 7;
    int sub = blockIdx.x >> 3;
    int nsub = gridDim.x >> 3;
    int lo = xcd * NPX;
    for (int i = sub * 256 + threadIdx.x; i < NE4; i += nsub * 256) {
        int4 d  = ((const int4*)edst)[i];
        int4 sr = ((const int4*)esrc)[i];
        #pragma unroll
        for (int c = 0; c < 4; ++c) {
            int dd = (c == 0) ? d.x : (c == 1) ? d.y : (c == 2) ? d.z : d.w;
            int ss = (c == 0) ? sr.x : (c == 1) ? sr.y : (c == 2) ? sr.z : sr.w;
            if ((unsigned)(dd - lo) < NPX) {
                int slot = atomicAdd(&deg[dd], 1);
                if (slot < CAP) {
                    bucket[dd * CAP + slot] = ss;
                } else {
                    int p = atomicAdd(spill_cnt, 1);
                    if (p < SPILL_MAX) { spill[2 * p] = dd; spill[2 * p + 1] = ss; }
                }
            }
        }
    }
}

__global__ __launch_bounds__(256) void dinv_kernel(const int* __restrict__ deg,
                                                   float* __restrict__ dinv) {
    int n = blockIdx.x * 256 + threadIdx.x;
    if (n < NN) dinv[n] = rsqrtf((float)(deg[n] + 1));  // +1 self loop
}

// ---------------- per-node matmul, fused finalize of previous layer ----------------
// MODE 0: v = x[n][f] (f32 input)
// MODE 1: v = relu(dinv[n]*a[n][f]+bias[f]) with a in bf16 (halved round-trip traffic)
// writes u[n] = bf16( dinv[n] * (v_row @ W) )
template <int MODE>
__global__ __launch_bounds__(256) void mm_kernel(const void* __restrict__ in,
                                                 const float* __restrict__ W,
                                                 const float* __restrict__ bias,
                                                 const float* __restrict__ dinv,
                                                 __hip_bfloat16* __restrict__ u) {
    __shared__ float Ws[64 * 64];
    __shared__ float hrow[4][64];
    int tid = threadIdx.x;
    {   // stage W (16 KB) via float4
        const float4* Wv = (const float4*)W;
        float4* Wsv = (float4*)Ws;
        #pragma unroll
        for (int i = 0; i < 4; ++i) Wsv[tid + 256 * i] = Wv[tid + 256 * i];
    }
    int local = tid >> 6;            // node within block
    int f = tid & 63;                // feature
    int n = blockIdx.x * 4 + local;  // NN divisible by 4
    float din = dinv[n];
    float v;
    if (MODE == 0) {
        v = ((const float*)in)[n * 64 + f];
    } else {
        v = __bfloat162float(((const __hip_bfloat16*)in)[n * 64 + f]);
        v = fmaxf(fmaf(din, v, bias[f]), 0.f);
    }
    hrow[local][f] = v;
    __syncthreads();
    float acc = 0.f;
    #pragma unroll
    for (int k = 0; k < 64; ++k)
        acc = fmaf(hrow[local][k], Ws[k * 64 + f], acc);
    u[n * 64 + f] = __float2bfloat16(din * acc);
}

// ---------------- aggregation core, G=8 (proven ~68us/layer floor) ----------------
__device__ __forceinline__ void acc_bf8(float acc[8], uint4 v) {
    acc[0] += __uint_as_float(v.x << 16);
    acc[1] += __uint_as_float(v.x & 0xffff0000u);
    acc[2] += __uint_as_float(v.y << 16);
    acc[3] += __uint_as_float(v.y & 0xffff0000u);
    acc[4] += __uint_as_float(v.z << 16);
    acc[5] += __uint_as_float(v.z & 0xffff0000u);
    acc[6] += __uint_as_float(v.w << 16);
    acc[7] += __uint_as_float(v.w & 0xffff0000u);
}

__device__ __forceinline__ unsigned packbf2(float lof, float hif) {
    __hip_bfloat16 l = __float2bfloat16(lof), h = __float2bfloat16(hif);
    unsigned short ul, uh;
    __builtin_memcpy(&ul, &l, 2);
    __builtin_memcpy(&uh, &h, 2);
    return ((unsigned)uh << 16) | ul;
}

// wave = 8 edge-groups x 8 lanes; group handles one edge per sweep, lane covers
// features [fo*8, fo*8+8) via one dwordx4 (16B): one load instruction = 8 x 128B
// gathers in flight. Bucket row batch-loaded once (coalesced) and broadcast by
// shfl. On exit acc[0..8) = aggregated row (self + neighbors), replicated
// across the 8 groups.
__device__ __forceinline__ void agg_row(const int* __restrict__ degv,
                                        const int* __restrict__ bucket,
                                        const uint4* __restrict__ u4,
                                        const int* __restrict__ spill,
                                        const int* __restrict__ spill_cnt,
                                        int n, int lane, int grp, int fo,
                                        float acc[8]) {
    float acc2[8];
    #pragma unroll
    for (int i = 0; i < 8; ++i) { acc[i] = 0.f; acc2[i] = 0.f; }
    int deg = degv[n];
    int dc = deg < CAP ? deg : CAP;
    int cidx = -1;
    if (lane < dc) cidx = bucket[n * CAP + lane];    // one coalesced row load
    if (grp == 0) acc_bf8(acc, u4[n * 8 + fo]);      // self loop
    int s0 = __shfl(cidx, grp);                      // sweep 0: edges 0..7
    int s1 = __shfl(cidx, grp + 8);                  // sweep 1: edges 8..15
    if (grp < dc) acc_bf8(acc, u4[s0 * 8 + fo]);
    if (grp + 8 < dc) acc_bf8(acc2, u4[s1 * 8 + fo]);
    for (int j = grp + 16; j < dc; j += 8) {         // deg in (16,64]
        int s = __shfl(cidx, j);
        acc_bf8(acc, u4[s * 8 + fo]);
    }
    if (deg > CAP) {                                 // spill drain: ~never taken
        int cnt = *spill_cnt; if (cnt > SPILL_MAX) cnt = SPILL_MAX;
        for (int e = 0; e < cnt; ++e) {
            if (spill[2 * e] == n && grp == 0)
                acc_bf8(acc2, u4[spill[2 * e + 1] * 8 + fo]);
        }
    }
    #pragma unroll
    for (int i = 0; i < 8; ++i) {                    // merge sweeps + 8 groups
        float v = acc[i] + acc2[i];
        v += __shfl_xor(v, 8);
        v += __shfl_xor(v, 16);
        v += __shfl_xor(v, 32);
        acc[i] = v;
    }
}

// ---------------- aggregate (POOL=0: a[n][:]=agg in bf16; POOL=1: fused global pool) ------------
// one wave per node, 100000 waves: max TLP, no serial nodes (R1/R2 lesson).
template <int POOL>
__global__ __launch_bounds__(256, 8) void agg_kernel(const int* __restrict__ degv,
                                                     const int* __restrict__ bucket,
                                                     const uint4* __restrict__ uin,
                                                     const float* __restrict__ dinv,
                                                     const int* __restrict__ spill,
                                                     const int* __restrict__ spill_cnt,
                                                     __hip_bfloat16* __restrict__ a,
                                                     float* __restrict__ gp) {
    __shared__ float gpart[64];
    int tid = threadIdx.x;
    if (POOL) {
        if (tid < 64) gpart[tid] = 0.f;
        __syncthreads();
    }
    int lane = tid & 63;
    int grp = lane >> 3;
    int fo = lane & 7;
    int n = blockIdx.x * 4 + (tid >> 6);              // NN divisible by 4
    float acc[8];
    agg_row(degv, bucket, uin, spill, spill_cnt, n, lane, grp, fo, acc);
    if (POOL) {
        if (grp == 0) {                               // lanes 0..7 hold the full row
            float din = dinv[n];
            #pragma unroll
            for (int i = 0; i < 8; ++i) atomicAdd(&gpart[fo * 8 + i], din * acc[i]);
        }
        __syncthreads();
        if (tid < 64) atomicAdd(&gp[(blockIdx.x & 63) * 64 + tid], gpart[tid]);
    } else {
        if (grp == 0) {                               // 8 lanes x 16B bf16 = the 128B row
            uint4 pv;
            pv.x = packbf2(acc[0], acc[1]);
            pv.y = packbf2(acc[2], acc[3]);
            pv.z = packbf2(acc[4], acc[5]);
            pv.w = packbf2(acc[6], acc[7]);
            ((uint4*)a)[n * 8 + fo] = pv;
        }
    }
}

// ---------------- head: g = colsum(gp) + N*b2;  out = g @ Wl + bl ----------------
__global__ __launch_bounds__(64) void head_kernel(const float* __restrict__ gp,
                                                  const float* __restrict__ b2,
                                                  const float* __restrict__ Wl,
                                                  const float* __restrict__ bl,
                                                  float* __restrict__ out) {
    int t = threadIdx.x;  // one wave
    float s = 0.f;
    #pragma unroll 8
    for (int r = 0; r < 64; ++r) s += gp[r * 64 + t];
    float gf = s + (float)NN * b2[t];
    #pragma unroll
    for (int c = 0; c < 10; ++c) {
        float p = gf * Wl[t * 10 + c];
        #pragma unroll
        for (int off = 32; off > 0; off >>= 1) p += __shfl_down(p, off);
        if (t == 0) out[c] = p + bl[c];
    }
}

extern "C" void kernel_launch(void* const* d_in, const int* in_sizes, int n_in,
                              void* d_out, int out_size, void* d_ws, size_t ws_size,
                              hipStream_t stream) {
    const float* x  = (const float*)d_in[0];
    const int* eidx = (const int*)d_in[1];
    const int* esrc = eidx;        // edge_idx[0]
    const int* edst = eidx + NE;   // edge_idx[1]
    const float* W0 = (const float*)d_in[2];
    const float* b0 = (const float*)d_in[3];
    const float* W1 = (const float*)d_in[4];
    const float* b1 = (const float*)d_in[5];
    const float* W2 = (const float*)d_in[6];
    const float* b2 = (const float*)d_in[7];
    const float* Wl = (const float*)d_in[8];
    const float* bl = (const float*)d_in[9];
    float* out = (float*)d_out;

    // workspace layout (4-byte units); u and a are 16B-aligned
    float* ws = (float*)d_ws;
    size_t off = 0;
    int*   deg    = (int*)(ws + off); off += NN;
    float* dinv   =        ws + off;  off += NN;
    __hip_bfloat16* u = (__hip_bfloat16*)(ws + off); off += (size_t)NN * 32;  // bf16 N*64
    __hip_bfloat16* a = (__hip_bfloat16*)(ws + off); off += (size_t)NN * 32;  // bf16 N*64
    float* gp     =        ws + off;  off += 64 * 64;                          // pool partials
    int*   spill_cnt = (int*)(ws + off); off += 4;                             // adjacent to gp: one memset
    int*   spill  = (int*)(ws + off); off += 2 * SPILL_MAX;
    int*   bucket = (int*)(ws + off); off += (size_t)NN * CAP;                 // 25.6 MB

    hipMemsetAsync(deg, 0, NN * sizeof(int), stream);
    hipMemsetAsync(gp, 0, (64 * 64 + 4) * sizeof(float), stream);  // gp + spill_cnt

    // single-pass bucket CSR build (normal dispatch: R5 proved coop launch breaks b&7->XCD)
    bucket_fill_kernel<<<2048, 256, 0, stream>>>(esrc, edst, deg, bucket, spill, spill_cnt);
    dinv_kernel<<<(NN + 255) / 256, 256, 0, stream>>>(deg, dinv);

    // layer 0
    mm_kernel<0><<<NN / 4, 256, 0, stream>>>(x, W0, nullptr, dinv, u);
    agg_kernel<0><<<NN / 4, 256, 0, stream>>>(deg, bucket, (const uint4*)u, dinv, spill, spill_cnt, a, gp);
    // layer 1
    mm_kernel<1><<<NN / 4, 256, 0, stream>>>(a, W1, b0, dinv, u);
    agg_kernel<0><<<NN / 4, 256, 0, stream>>>(deg, bucket, (const uint4*)u, dinv, spill, spill_cnt, a, gp);
    // layer 2
    mm_kernel<1><<<NN / 4, 256, 0, stream>>>(a, W2, b1, dinv, u);
    // fused: agg(layer2) + global pool (dinv folded; N*b2 added in head)
    agg_kernel<1><<<NN / 4, 256, 0, stream>>>(deg, bucket, (const uint4*)u, dinv, spill, spill_cnt, a, gp);
    head_kernel<<<1, 64, 0, stream>>>(gp, b2, Wl, bl, out);
}

// Round 7
// 333.451 us; speedup vs baseline: 2.5894x; 1.0363x over previous
//
#include <hip/hip_runtime.h>
#include <hip/hip_bf16.h>

#define NN 100000
#define NE 1200000
#define NE4 (NE / 4)                         // 300000
#define XCD_N 8
#define NPX (NN / XCD_N)                     // 12500 nodes per XCD
#define CAP 64                               // bucket capacity (P(deg>64) ~ 15 sigma)
#define SPILL_MAX 4096

// ---------------- single-pass CSR-bucket build, XCD-partitioned ----------------
// block b (XCD = b&7, normal dispatch only -- R5 showed coop launch breaks this
// mapping) stripes the full edge list with its XCD's sibling blocks and handles
// only dsts in its 12500-node range: deg lines and bucket lines are written by
// exactly one XCD -> L2-local lines, dirty lines evict once (R3: 85MB HBM
// writes for 4.8MB payload without ownership). Returning atomicAdd gives the
// slot; deg ends as the true degree. Slots >= CAP go to a spill list (never in
// practice; drained inside agg for correctness).
__global__ __launch_bounds__(256) void bucket_fill_kernel(const int* __restrict__ esrc,
                                                          const int* __restrict__ edst,
                                                          int* __restrict__ deg,
                                                          int* __restrict__ bucket,
                                                          int* __restrict__ spill,
                                                          int* __restrict__ spill_cnt) {
    int xcd = blockIdx.x & 7;
    int sub = blockIdx.x >> 3;
    int nsub = gridDim.x >> 3;
    int lo = xcd * NPX;
    for (int i = sub * 256 + threadIdx.x; i < NE4; i += nsub * 256) {
        int4 d  = ((const int4*)edst)[i];
        int4 sr = ((const int4*)esrc)[i];
        #pragma unroll
        for (int c = 0; c < 4; ++c) {
            int dd = (c == 0) ? d.x : (c == 1) ? d.y : (c == 2) ? d.z : d.w;
            int ss = (c == 0) ? sr.x : (c == 1) ? sr.y : (c == 2) ? sr.z : sr.w;
            if ((unsigned)(dd - lo) < NPX) {
                int slot = atomicAdd(&deg[dd], 1);
                if (slot < CAP) {
                    bucket[dd * CAP + slot] = ss;
                } else {
                    int p = atomicAdd(spill_cnt, 1);
                    if (p < SPILL_MAX) { spill[2 * p] = dd; spill[2 * p + 1] = ss; }
                }
            }
        }
    }
}

// ---------------- layer-0 matmul: u = bf16(din * (x @ W0)) ----------------
__global__ __launch_bounds__(256) void mm0_kernel(const float* __restrict__ in,
                                                  const float* __restrict__ W,
                                                  const int* __restrict__ deg,
                                                  __hip_bfloat16* __restrict__ u) {
    __shared__ float Ws[64 * 64];
    __shared__ float hrow[4][64];
    int tid = threadIdx.x;
    {   // stage W (16 KB) via float4
        const float4* Wv = (const float4*)W;
        float4* Wsv = (float4*)Ws;
        #pragma unroll
        for (int i = 0; i < 4; ++i) Wsv[tid + 256 * i] = Wv[tid + 256 * i];
    }
    int local = tid >> 6;            // node within block
    int f = tid & 63;                // feature
    int n = blockIdx.x * 4 + local;  // NN divisible by 4
    float din = rsqrtf((float)(deg[n] + 1));
    hrow[local][f] = in[n * 64 + f];
    __syncthreads();
    float acc = 0.f;
    #pragma unroll
    for (int k = 0; k < 64; ++k)
        acc = fmaf(hrow[local][k], Ws[k * 64 + f], acc);
    u[n * 64 + f] = __float2bfloat16(din * acc);
}

// ---------------- aggregation core, G=8 (proven ~68us/layer floor) ----------------
__device__ __forceinline__ void acc_bf8(float acc[8], uint4 v) {
    acc[0] += __uint_as_float(v.x << 16);
    acc[1] += __uint_as_float(v.x & 0xffff0000u);
    acc[2] += __uint_as_float(v.y << 16);
    acc[3] += __uint_as_float(v.y & 0xffff0000u);
    acc[4] += __uint_as_float(v.z << 16);
    acc[5] += __uint_as_float(v.z & 0xffff0000u);
    acc[6] += __uint_as_float(v.w << 16);
    acc[7] += __uint_as_float(v.w & 0xffff0000u);
}

// wave = 8 edge-groups x 8 lanes; group handles one edge per sweep, lane covers
// features [fo*8, fo*8+8) via one dwordx4 (16B): one load instruction = 8 x 128B
// gathers in flight. Bucket row batch-loaded once (coalesced) and broadcast by
// shfl. On exit acc[0..8) = aggregated row (self + neighbors), replicated
// across the 8 groups.
__device__ __forceinline__ void agg_row(const int* __restrict__ degv,
                                        const int* __restrict__ bucket,
                                        const uint4* __restrict__ u4,
                                        const int* __restrict__ spill,
                                        const int* __restrict__ spill_cnt,
                                        int n, int lane, int grp, int fo,
                                        float acc[8]) {
    float acc2[8];
    #pragma unroll
    for (int i = 0; i < 8; ++i) { acc[i] = 0.f; acc2[i] = 0.f; }
    int deg = degv[n];
    int dc = deg < CAP ? deg : CAP;
    int cidx = -1;
    if (lane < dc) cidx = bucket[n * CAP + lane];    // one coalesced row load
    if (grp == 0) acc_bf8(acc, u4[n * 8 + fo]);      // self loop
    int s0 = __shfl(cidx, grp);                      // sweep 0: edges 0..7
    int s1 = __shfl(cidx, grp + 8);                  // sweep 1: edges 8..15
    if (grp < dc) acc_bf8(acc, u4[s0 * 8 + fo]);
    if (grp + 8 < dc) acc_bf8(acc2, u4[s1 * 8 + fo]);
    for (int j = grp + 16; j < dc; j += 8) {         // deg in (16,64]
        int s = __shfl(cidx, j);
        acc_bf8(acc, u4[s * 8 + fo]);
    }
    if (deg > CAP) {                                 // spill drain: ~never taken
        int cnt = *spill_cnt; if (cnt > SPILL_MAX) cnt = SPILL_MAX;
        for (int e = 0; e < cnt; ++e) {
            if (spill[2 * e] == n && grp == 0)
                acc_bf8(acc2, u4[spill[2 * e + 1] * 8 + fo]);
        }
    }
    #pragma unroll
    for (int i = 0; i < 8; ++i) {                    // merge sweeps + 8 groups
        float v = acc[i] + acc2[i];
        v += __shfl_xor(v, 8);
        v += __shfl_xor(v, 16);
        v += __shfl_xor(v, 32);
        acc[i] = v;
    }
}

// ---------------- fused aggregate + finalize + next-layer matmul ----------------
// per node n (one wave, 100000 waves -- R1/R2 lesson: never serialize nodes):
//   acc = u[n] + sum_{src} u[src]                      (gather, memory-floor bound)
//   t   = relu(din*acc + bias)                          (finalize prev layer)
//   uout[n] = bf16( din * (t @ W) )                     (LDS-broadcast matmul,
// ~700cy of LDS/VALU per wave that hides under the ~68us gather memory floor:
// VALUBusy is only 32% there). No block barrier after staging W: hrow is
// per-wave, written and read by the same wave (in-order LDS).
__global__ __launch_bounds__(256, 6) void aggmm_kernel(const int* __restrict__ degv,
                                                       const int* __restrict__ bucket,
                                                       const uint4* __restrict__ uin,
                                                       const int* __restrict__ spill,
                                                       const int* __restrict__ spill_cnt,
                                                       const float* __restrict__ bias,
                                                       const float* __restrict__ W,
                                                       __hip_bfloat16* __restrict__ uout) {
    __shared__ float Ws[64 * 64];
    __shared__ float hrow[4][64];
    int tid = threadIdx.x;
    {   // stage W (16 KB) via float4
        const float4* Wv = (const float4*)W;
        float4* Wsv = (float4*)Ws;
        #pragma unroll
        for (int i = 0; i < 4; ++i) Wsv[tid + 256 * i] = Wv[tid + 256 * i];
    }
    __syncthreads();
    int wid = tid >> 6;
    int lane = tid & 63;
    int grp = lane >> 3;
    int fo = lane & 7;
    int n = blockIdx.x * 4 + wid;                     // NN divisible by 4
    float acc[8];
    agg_row(degv, bucket, uin, spill, spill_cnt, n, lane, grp, fo, acc);
    float din = rsqrtf((float)(degv[n] + 1));
    if (grp == 0) {                                   // lanes 0..7 hold the full row
        float4 blo = ((const float4*)bias)[fo * 2];
        float4 bhi = ((const float4*)bias)[fo * 2 + 1];
        float4 lo, hi;
        lo.x = fmaxf(fmaf(din, acc[0], blo.x), 0.f);
        lo.y = fmaxf(fmaf(din, acc[1], blo.y), 0.f);
        lo.z = fmaxf(fmaf(din, acc[2], blo.z), 0.f);
        lo.w = fmaxf(fmaf(din, acc[3], blo.w), 0.f);
        hi.x = fmaxf(fmaf(din, acc[4], bhi.x), 0.f);
        hi.y = fmaxf(fmaf(din, acc[5], bhi.y), 0.f);
        hi.z = fmaxf(fmaf(din, acc[6], bhi.z), 0.f);
        hi.w = fmaxf(fmaf(din, acc[7], bhi.w), 0.f);
        ((float4*)hrow[wid])[fo * 2] = lo;            // t row -> per-wave LDS
        ((float4*)hrow[wid])[fo * 2 + 1] = hi;
    }
    // same-wave LDS RAW (write above, read below): in-order LDS + compiler
    // lgkmcnt ordering through the shared array; no barrier needed.
    float o = 0.f;
    const float4* hv = (const float4*)hrow[wid];
    #pragma unroll
    for (int k4 = 0; k4 < 16; ++k4) {
        float4 h = hv[k4];                            // broadcast read (all lanes same addr)
        int kb = k4 * 4;
        o = fmaf(h.x, Ws[(kb + 0) * 64 + lane], o);
        o = fmaf(h.y, Ws[(kb + 1) * 64 + lane], o);
        o = fmaf(h.z, Ws[(kb + 2) * 64 + lane], o);
        o = fmaf(h.w, Ws[(kb + 3) * 64 + lane], o);
    }
    uout[n * 64 + lane] = __float2bfloat16(din * o);
}

// ---------------- final aggregate + global pool: gp += din*agg ----------------
__global__ __launch_bounds__(256, 6) void aggpool_kernel(const int* __restrict__ degv,
                                                         const int* __restrict__ bucket,
                                                         const uint4* __restrict__ uin,
                                                         const int* __restrict__ spill,
                                                         const int* __restrict__ spill_cnt,
                                                         float* __restrict__ gp) {
    __shared__ float gpart[64];
    int tid = threadIdx.x;
    if (tid < 64) gpart[tid] = 0.f;
    __syncthreads();
    int lane = tid & 63;
    int grp = lane >> 3;
    int fo = lane & 7;
    int n = blockIdx.x * 4 + (tid >> 6);              // NN divisible by 4
    float acc[8];
    agg_row(degv, bucket, uin, spill, spill_cnt, n, lane, grp, fo, acc);
    if (grp == 0) {                                   // lanes 0..7 hold the full row
        float din = rsqrtf((float)(degv[n] + 1));
        #pragma unroll
        for (int i = 0; i < 8; ++i) atomicAdd(&gpart[fo * 8 + i], din * acc[i]);
    }
    __syncthreads();
    if (tid < 64) atomicAdd(&gp[(blockIdx.x & 63) * 64 + tid], gpart[tid]);
}

// ---------------- head: g = colsum(gp) + N*b2;  out = g @ Wl + bl ----------------
__global__ __launch_bounds__(64) void head_kernel(const float* __restrict__ gp,
                                                  const float* __restrict__ b2,
                                                  const float* __restrict__ Wl,
                                                  const float* __restrict__ bl,
                                                  float* __restrict__ out) {
    int t = threadIdx.x;  // one wave
    float s = 0.f;
    #pragma unroll 8
    for (int r = 0; r < 64; ++r) s += gp[r * 64 + t];
    float gf = s + (float)NN * b2[t];
    #pragma unroll
    for (int c = 0; c < 10; ++c) {
        float p = gf * Wl[t * 10 + c];
        #pragma unroll
        for (int off = 32; off > 0; off >>= 1) p += __shfl_down(p, off);
        if (t == 0) out[c] = p + bl[c];
    }
}

extern "C" void kernel_launch(void* const* d_in, const int* in_sizes, int n_in,
                              void* d_out, int out_size, void* d_ws, size_t ws_size,
                              hipStream_t stream) {
    const float* x  = (const float*)d_in[0];
    const int* eidx = (const int*)d_in[1];
    const int* esrc = eidx;        // edge_idx[0]
    const int* edst = eidx + NE;   // edge_idx[1]
    const float* W0 = (const float*)d_in[2];
    const float* b0 = (const float*)d_in[3];
    const float* W1 = (const float*)d_in[4];
    const float* b1 = (const float*)d_in[5];
    const float* W2 = (const float*)d_in[6];
    const float* b2 = (const float*)d_in[7];
    const float* Wl = (const float*)d_in[8];
    const float* bl = (const float*)d_in[9];
    float* out = (float*)d_out;

    // workspace layout (4-byte units); ua/ub are 16B-aligned
    float* ws = (float*)d_ws;
    size_t off = 0;
    int*   deg    = (int*)(ws + off); off += NN;
    __hip_bfloat16* ua = (__hip_bfloat16*)(ws + off); off += (size_t)NN * 32;  // bf16 N*64
    __hip_bfloat16* ub = (__hip_bfloat16*)(ws + off); off += (size_t)NN * 32;  // bf16 N*64
    float* gp     =        ws + off;  off += 64 * 64;                          // pool partials
    int*   spill_cnt = (int*)(ws + off); off += 4;                             // adjacent to gp: one memset
    int*   spill  = (int*)(ws + off); off += 2 * SPILL_MAX;
    int*   bucket = (int*)(ws + off); off += (size_t)NN * CAP;                 // 25.6 MB

    hipMemsetAsync(deg, 0, NN * sizeof(int), stream);
    hipMemsetAsync(gp, 0, (64 * 64 + 4) * sizeof(float), stream);  // gp + spill_cnt

    // single-pass bucket CSR build (normal dispatch: R5 proved coop launch breaks b&7->XCD)
    bucket_fill_kernel<<<2048, 256, 0, stream>>>(esrc, edst, deg, bucket, spill, spill_cnt);

    // layer 0 matmul: ua = bf16(din*(x@W0))
    mm0_kernel<<<NN / 4, 256, 0, stream>>>(x, W0, deg, ua);
    // fused: agg(ua) + relu/bias(b0) + matmul(W1) -> ub
    aggmm_kernel<<<NN / 4, 256, 0, stream>>>(deg, bucket, (const uint4*)ua, spill, spill_cnt, b0, W1, ub);
    // fused: agg(ub) + relu/bias(b1) + matmul(W2) -> ua
    aggmm_kernel<<<NN / 4, 256, 0, stream>>>(deg, bucket, (const uint4*)ub, spill, spill_cnt, b1, W2, ua);
    // fused: agg(ua) + global pool (din folded; N*b2 added in head)
    aggpool_kernel<<<NN / 4, 256, 0, stream>>>(deg, bucket, (const uint4*)ua, spill, spill_cnt, gp);
    head_kernel<<<1, 64, 0, stream>>>(gp, b2, Wl, bl, out);
}